// Round 4
// baseline (63.564 us; speedup 1.0000x reference)
//
#include <hip/hip_runtime.h>

// SigKernel: X (32,256,8) f32, Y (32,256,8) f32 -> out (32,32) f32.
// refinement=1.0 => interpolation identity; scale=1.0 => a_ij = dot(dX[i-1], dY[j-1]).
// Goursat PDE on 256x256 grid, boundary K[i][0]=K[0][j]=1:
//   f1 = 1 + a/2 + a^2/12, f2 = 1 - a^2/12
//   K[i][j] = (K[i][j-1] + K[i-1][j])*f1 - K[i-1][j-1]*f2 ; out = K[255][255]
//
// 1 wave per pair. TWO skewed strips per wave, interleaved so their dependency
// chains hide under each other's issue:
//   front : rows 1..128  (lane l owns 2l+1, 2l+2), col j = s - l,      s=1..318
//   lagged: rows 129..255 (lane l owns 129+2l,130+2l), col j = s-l-64, s=65..382
// Row-128 values cross front->lagged via a 64-slot LDS ring (same wave,
// in-order DS pipe, no barrier; write slot (s+1)&63, read slot s&63).
// Branch-free column edges via zero-padded dy (dy=0 -> identity update).

typedef float f32x2 __attribute__((ext_vector_type(2)));
typedef float f32x4 __attribute__((ext_vector_type(4)));

#define MM    255
#define DYST  9          // odd float stride -> conflict-free b32 LDS reads
#define DYOFF 127        // increment ji stored at (ji + DYOFF)*DYST
#define DYSZ  4608       // covers max prefetch idx (445*9+7=4012) with slack

static __device__ inline f32x2 fma2(f32x2 a, f32x2 b, f32x2 c) {
    return __builtin_elementwise_fma(a, b, c);
}

__global__ __launch_bounds__(64) void sigker_dual(
    const float* __restrict__ X,
    const float* __restrict__ Y,
    float* __restrict__ out)
{
    const int pair = blockIdx.x;      // 0..1023
    const int ax = pair >> 5;
    const int by = pair & 31;
    const int l  = threadIdx.x;       // 0..63

    __shared__ float dYs[DYSZ];
    __shared__ float ring[64];        // row-128 history, slot = col & 63

    const float* Xa = X + ax * 2048;
    const float* Yb = Y + by * 2048;

    // Zero-fill pads (vec4 stores), ring = 1.0 (boundary K[128][j<=0] = 1).
    f32x4* dz = (f32x4*)dYs;
    #pragma unroll
    for (int v = 0; v < DYSZ / 4; v += 64) dz[v + l] = (f32x4){0, 0, 0, 0};
    ring[l] = 1.0f;
    __syncthreads();

    // Stage dY increments: lane l covers ji = 4l .. 4l+3 (ji <= 254).
    {
        f32x4 g[10];
        const f32x4* Yv = (const f32x4*)(Yb + l * 32);
        #pragma unroll
        for (int k = 0; k < 8; ++k) g[k] = Yv[k];
        g[8] = (l < 63) ? Yv[8] : (f32x4){0, 0, 0, 0};
        g[9] = (l < 63) ? Yv[9] : (f32x4){0, 0, 0, 0};
        #pragma unroll
        for (int r = 0; r < 4; ++r) {
            const int ji = 4 * l + r;
            if (ji <= MM - 1) {
                #pragma unroll
                for (int c = 0; c < 8; ++c) {
                    const int e = r * 8 + c;
                    const float v0 = g[e >> 2][e & 3];
                    const float v1 = g[(e + 8) >> 2][(e + 8) & 3];
                    dYs[(ji + DYOFF) * DYST + c] = v1 - v0;
                }
            }
        }
    }

    // dx pairs. Front rows 2l+1,2l+2 need X rows 2l..2l+2 (floats 16l..16l+24).
    // Lagged rows 129+2l,130+2l need X rows 128+2l..130+2l; lane 63 row 256 OOB -> 0.
    f32x2 dxF[8], dxL[8];
    {
        const f32x4* Xv = (const f32x4*)(Xa + l * 16);
        f32x4 f[6];
        #pragma unroll
        for (int k = 0; k < 6; ++k) f[k] = Xv[k];
        #pragma unroll
        for (int c = 0; c < 8; ++c) {
            const float e0 = f[c >> 2][c & 3];
            const float e1 = f[(8 + c) >> 2][(8 + c) & 3];
            const float e2 = f[(16 + c) >> 2][(16 + c) & 3];
            dxF[c] = (f32x2){e1 - e0, e2 - e1};
        }
        const f32x4* Xw = (const f32x4*)(Xa + 1024 + l * 16);
        f32x4 h[6];
        #pragma unroll
        for (int k = 0; k < 4; ++k) h[k] = Xw[k];
        h[4] = (l < 63) ? Xw[4] : (f32x4){0, 0, 0, 0};
        h[5] = (l < 63) ? Xw[5] : (f32x4){0, 0, 0, 0};
        #pragma unroll
        for (int c = 0; c < 8; ++c) {
            const float e0 = h[c >> 2][c & 3];
            const float e1 = h[(8 + c) >> 2][(8 + c) & 3];
            const float e2 = h[(16 + c) >> 2][(16 + c) & 3];
            dxL[c] = (f32x2){e1 - e0, e2 - e1};
        }
    }
    __syncthreads();

    const f32x2 C12  = { 1.0f / 12.0f,  1.0f / 12.0f};
    const f32x2 CN12 = {-1.0f / 12.0f, -1.0f / 12.0f};
    const f32x2 CH   = { 0.5f, 0.5f};
    const f32x2 C1   = { 1.0f, 1.0f};

    float KF0 = 1.0f, KF1 = 1.0f, updF = 1.0f;
    float KL0 = 1.0f, KL1 = 1.0f, updL = 1.0f;

    int baseF = (127 - l) * DYST;     // idx for col jF = 1-l at s=1
    float dyF[8], dyL[8];
    #pragma unroll
    for (int c = 0; c < 8; ++c) dyF[c] = dYs[baseF + c];

#define FRONT_STEP(s_) {                                                     \
    const int nbF = baseF + DYST;                                            \
    float nF0 = dYs[nbF+0], nF1 = dYs[nbF+1], nF2 = dYs[nbF+2],              \
          nF3 = dYs[nbF+3], nF4 = dYs[nbF+4], nF5 = dYs[nbF+5],              \
          nF6 = dYs[nbF+6], nF7 = dYs[nbF+7];                                \
    float upF = __shfl_up(KF1, 1); if (l == 0) upF = 1.0f;                   \
    f32x2 aF = dxF[0] * (f32x2){dyF[0], dyF[0]};                             \
    aF = fma2(dxF[1], (f32x2){dyF[1], dyF[1]}, aF);                          \
    aF = fma2(dxF[2], (f32x2){dyF[2], dyF[2]}, aF);                          \
    aF = fma2(dxF[3], (f32x2){dyF[3], dyF[3]}, aF);                          \
    aF = fma2(dxF[4], (f32x2){dyF[4], dyF[4]}, aF);                          \
    aF = fma2(dxF[5], (f32x2){dyF[5], dyF[5]}, aF);                          \
    aF = fma2(dxF[6], (f32x2){dyF[6], dyF[6]}, aF);                          \
    aF = fma2(dxF[7], (f32x2){dyF[7], dyF[7]}, aF);                          \
    const f32x2 qF  = aF * aF;                                               \
    const f32x2 f1F = fma2(qF, C12, fma2(aF, CH, C1));                       \
    const f32x2 f2F = fma2(qF, CN12, C1);                                    \
    const f32x2 tF  = (f32x2){updF, KF0} * f2F;                              \
    const float kF0 = fmaf(KF0 + upF, f1F.x, -tF.x);                         \
    const float kF1 = fmaf(KF1 + kF0, f1F.y, -tF.y);                         \
    updF = upF; KF0 = kF0; KF1 = kF1;                                        \
    if (l == 63) ring[((s_) + 1) & 63] = kF1;                                \
    dyF[0]=nF0; dyF[1]=nF1; dyF[2]=nF2; dyF[3]=nF3;                          \
    dyF[4]=nF4; dyF[5]=nF5; dyF[6]=nF6; dyF[7]=nF7;                          \
    baseF = nbF; }

#define LAG_STEP(s_) {                                                       \
    const int nbL = baseL + DYST;                                            \
    float nL0 = dYs[nbL+0], nL1 = dYs[nbL+1], nL2 = dYs[nbL+2],              \
          nL3 = dYs[nbL+3], nL4 = dYs[nbL+4], nL5 = dYs[nbL+5],              \
          nL6 = dYs[nbL+6], nL7 = dYs[nbL+7];                                \
    const float rg = ring[(s_) & 63];                                        \
    float upL = __shfl_up(KL1, 1); if (l == 0) upL = rg;                     \
    f32x2 aL = dxL[0] * (f32x2){dyL[0], dyL[0]};                             \
    aL = fma2(dxL[1], (f32x2){dyL[1], dyL[1]}, aL);                          \
    aL = fma2(dxL[2], (f32x2){dyL[2], dyL[2]}, aL);                          \
    aL = fma2(dxL[3], (f32x2){dyL[3], dyL[3]}, aL);                          \
    aL = fma2(dxL[4], (f32x2){dyL[4], dyL[4]}, aL);                          \
    aL = fma2(dxL[5], (f32x2){dyL[5], dyL[5]}, aL);                          \
    aL = fma2(dxL[6], (f32x2){dyL[6], dyL[6]}, aL);                          \
    aL = fma2(dxL[7], (f32x2){dyL[7], dyL[7]}, aL);                          \
    const f32x2 qL  = aL * aL;                                               \
    const f32x2 f1L = fma2(qL, C12, fma2(aL, CH, C1));                       \
    const f32x2 f2L = fma2(qL, CN12, C1);                                    \
    const f32x2 tL  = (f32x2){updL, KL0} * f2L;                              \
    const float kL0 = fmaf(KL0 + upL, f1L.x, -tL.x);                         \
    const float kL1 = fmaf(KL1 + kL0, f1L.y, -tL.y);                         \
    updL = upL; KL0 = kL0; KL1 = kL1;                                        \
    dyL[0]=nL0; dyL[1]=nL1; dyL[2]=nL2; dyL[3]=nL3;                          \
    dyL[4]=nL4; dyL[5]=nL5; dyL[6]=nL6; dyL[7]=nL7;                          \
    baseL = nbL; }

    // Phase A: front only, s = 1..64 (primes ring slots for cols 1..)
    #pragma unroll 2
    for (int s = 1; s <= 64; ++s) FRONT_STEP(s);

    // Phase B: both strips, s = 65..318. Lagged col = s-64 starts at 1.
    int baseL = (127 - l) * DYST;     // idx for col jL = 1-l at s=65
    #pragma unroll
    for (int c = 0; c < 8; ++c) dyL[c] = dYs[baseL + c];

    #pragma unroll 2
    for (int s = 65; s <= 318; ++s) { FRONT_STEP(s); LAG_STEP(s); }

    // Phase C: lagged only, s = 319..382 (front done; ring fully written).
    #pragma unroll 2
    for (int s = 319; s <= 382; ++s) LAG_STEP(s);

    // Row 255 = lagged lane 63 first row, last updated at s=382 (col 255).
    if (l == 63) out[pair] = KL0;

#undef FRONT_STEP
#undef LAG_STEP
}

extern "C" void kernel_launch(void* const* d_in, const int* in_sizes, int n_in,
                              void* d_out, int out_size, void* d_ws, size_t ws_size,
                              hipStream_t stream)
{
    const float* X = (const float*)d_in[0];
    const float* Y = (const float*)d_in[1];
    float* out = (float*)d_out;
    (void)in_sizes; (void)n_in; (void)out_size; (void)d_ws; (void)ws_size;

    sigker_dual<<<dim3(32 * 32), dim3(64), 0, stream>>>(X, Y, out);
}

// Round 5
// 41.028 us; speedup vs baseline: 1.5493x; 1.5493x over previous
//
#include <hip/hip_runtime.h>

// SigKernel: X (32,256,8) f32, Y (32,256,8) f32 -> out (32,32) f32.
// refinement=1.0 => interpolation identity; scale=1.0 => a_ij = dot(dX[i-1], dY[j-1]).
// Goursat PDE on 256x256 grid, boundary K[i][0]=K[0][j]=1:
//   f1 = 1 + a/2 + a^2/12, f2 = 1 - a^2/12
//   K[i][j] = (K[i][j-1] + K[i-1][j])*f1 - K[i-1][j-1]*f2 ; out = K[255][255]
//
// 1 wave per pair, lane l owns rows 4l+1..4l+4, skewed column march (step s,
// lane l -> column j = s-l). Branch-free edges via zero-padded dy (dy=0 ->
// f1=f2=1 -> identity update preserves boundary/frozen values).
//
// Round-5 structure:
//  - inter-lane dep via v_mov_b32_dpp wave_shr:1 (VALU, ~4cy) instead of
//    ds_bpermute; old-operand = 1.0f gives lane 0 the row-0 boundary free.
//  - recurrence refactored to 1 fma/cell chain: k_r = fmaf(k_{r-1}, f1_r, c_r),
//    c_r = fmaf(K_r, f1_r, -kupd_r*f2_r) off-chain.
//  - factors computed one step ahead; dy prefetched two steps ahead.

typedef float f32x2 __attribute__((ext_vector_type(2)));
typedef float f32x4 __attribute__((ext_vector_type(4)));

#define MM   255
#define DYST 9            // odd float stride -> conflict-free b32 LDS reads
#define DYSZ 3456         // max idx (382)*9+7 = 3445 < 3456

static __device__ inline f32x2 fma2(f32x2 a, f32x2 b, f32x2 c) {
    return __builtin_elementwise_fma(a, b, c);
}

// up[l] = (l==0) ? 1.0f : x[l-1]  -- one v_mov_b32_dpp wave_shr:1
static __device__ inline float shr1_or_one(float x) {
    int r = __builtin_amdgcn_update_dpp(
        __float_as_int(1.0f), __float_as_int(x),
        0x138 /* wave_shr:1 */, 0xF, 0xF, false);
    return __int_as_float(r);
}

__global__ __launch_bounds__(64) void sigker_dpp(
    const float* __restrict__ X,
    const float* __restrict__ Y,
    float* __restrict__ out)
{
    const int pair = blockIdx.x;      // 0..1023
    const int ax = pair >> 5;
    const int by = pair & 31;
    const int l  = threadIdx.x;       // 0..63

    __shared__ float dYs[DYSZ];

    const float* Xa = X + ax * 2048;
    const float* Yb = Y + by * 2048;

    // Zero-fill pads (vec4), then stage real dY increments at (ji+63)*9 + c.
    {
        f32x4* dz = (f32x4*)dYs;
        #pragma unroll
        for (int v = l; v < DYSZ / 4; v += 64) dz[v] = (f32x4){0, 0, 0, 0};
    }
    __syncthreads();
    for (int v = l; v < MM * 8; v += 64) {
        const int j = v >> 3, c = v & 7;
        dYs[(j + 63) * DYST + c] = Yb[(j + 1) * 8 + c] - Yb[j * 8 + c];
    }

    // dx rows 4l+1..4l+4 from contiguous window [4l*8, 4l*8+40) of Xa.
    // Lane 63 tail (row 256) OOB -> zero (its K3 feeds nothing).
    f32x2 dxp0[8], dxp1[8];   // {r0,r1}, {r2,r3} per dim
    {
        f32x4 f[10];
        const f32x4* Xv = (const f32x4*)(Xa + l * 32);
        #pragma unroll
        for (int k = 0; k < 8; ++k) f[k] = Xv[k];
        f[8] = (l < 63) ? Xv[8] : (f32x4){0, 0, 0, 0};
        f[9] = (l < 63) ? Xv[9] : (f32x4){0, 0, 0, 0};
        #pragma unroll
        for (int c = 0; c < 8; ++c) {
            const float e0 = f[(c)      >> 2][(c)      & 3];
            const float e1 = f[(8 + c)  >> 2][(8 + c)  & 3];
            const float e2 = f[(16 + c) >> 2][(16 + c) & 3];
            const float e3 = f[(24 + c) >> 2][(24 + c) & 3];
            const float e4 = f[(32 + c) >> 2][(32 + c) & 3];
            dxp0[c] = (f32x2){e1 - e0, e2 - e1};
            dxp1[c] = (f32x2){e3 - e2, e4 - e3};
        }
    }
    __syncthreads();

    const f32x2 C12  = { 1.0f / 12.0f,  1.0f / 12.0f};
    const f32x2 CN12 = {-1.0f / 12.0f, -1.0f / 12.0f};
    const f32x2 CH   = { 0.5f, 0.5f};
    const f32x2 C1   = { 1.0f, 1.0f};

    // factors(dy) -> f1a,f1b,f2a,f2b (packed over row pairs)
    auto factors = [&](const float* dy, f32x2& f1a, f32x2& f1b,
                       f32x2& f2a, f32x2& f2b) {
        f32x2 b = (f32x2){dy[0], dy[0]};
        f32x2 a01 = dxp0[0] * b, a23 = dxp1[0] * b;
        #pragma unroll
        for (int c = 1; c < 8; ++c) {
            b = (f32x2){dy[c], dy[c]};
            a01 = fma2(dxp0[c], b, a01);
            a23 = fma2(dxp1[c], b, a23);
        }
        const f32x2 q01 = a01 * a01, q23 = a23 * a23;
        f1a = fma2(q01, C12, fma2(a01, CH, C1));
        f1b = fma2(q23, C12, fma2(a23, CH, C1));
        f2a = fma2(q01, CN12, C1);
        f2b = fma2(q23, CN12, C1);
    };

    float K0 = 1.0f, K1 = 1.0f, K2 = 1.0f, K3 = 1.0f, upd = 1.0f;

    const int base = (63 - l) * DYST;    // dy idx for step s: (s-1-l+63)*9
    float dyN[8];                        // dy for step s+1
    f32x2 f1a, f1b, f2a, f2b;            // factors for step s
    {
        float dyA[8];
        #pragma unroll
        for (int c = 0; c < 8; ++c) dyA[c] = dYs[base + c];
        factors(dyA, f1a, f1b, f2a, f2b);
        #pragma unroll
        for (int c = 0; c < 8; ++c) dyN[c] = dYs[base + DYST + c];
    }
    int pbase = base + 2 * DYST;         // prefetch idx: dy for step s+2

    #pragma unroll 2
    for (int s = 1; s <= MM + 63; ++s) {     // 318 steps
        // Prefetch dy(s+2) -- consumed at the bottom of the NEXT iteration.
        float dyP[8];
        #pragma unroll
        for (int c = 0; c < 8; ++c) dyP[c] = dYs[pbase + c];

        // Inter-lane dependency: up = K3[lane-1], lane0 -> 1.0 (boundary).
        const float up = shr1_or_one(K3);

        // Off-chain constants: c_r = K_r*f1_r - kupd_r*f2_r.
        const float t0 = upd * f2a.x;
        const float t1 = K0  * f2a.y;
        const float t2 = K1  * f2b.x;
        const float t3 = K2  * f2b.y;
        const float c0 = fmaf(K0, f1a.x, -t0);
        const float c1 = fmaf(K1, f1a.y, -t1);
        const float c2 = fmaf(K2, f1b.x, -t2);
        const float c3 = fmaf(K3, f1b.y, -t3);

        // Serial chain: 4 dependent fmas.
        const float k0 = fmaf(up, f1a.x, c0);
        const float k1 = fmaf(k0, f1a.y, c1);
        const float k2 = fmaf(k1, f1b.x, c2);
        const float k3 = fmaf(k2, f1b.y, c3);

        upd = up; K0 = k0; K1 = k1; K2 = k2; K3 = k3;

        // Factors for step s+1 from dyN (loaded a full iteration ago).
        factors(dyN, f1a, f1b, f2a, f2b);

        // Rotate prefetch registers.
        #pragma unroll
        for (int c = 0; c < 8; ++c) dyN[c] = dyP[c];
        pbase += DYST;
    }

    // Row 255 = lane 63, local r=2; last real update at s=318 (j=255).
    if (l == 63) out[pair] = K2;
}

extern "C" void kernel_launch(void* const* d_in, const int* in_sizes, int n_in,
                              void* d_out, int out_size, void* d_ws, size_t ws_size,
                              hipStream_t stream)
{
    const float* X = (const float*)d_in[0];
    const float* Y = (const float*)d_in[1];
    float* out = (float*)d_out;
    (void)in_sizes; (void)n_in; (void)out_size; (void)d_ws; (void)ws_size;

    sigker_dpp<<<dim3(32 * 32), dim3(64), 0, stream>>>(X, Y, out);
}